// Round 17
// baseline (445.290 us; speedup 1.0000x reference)
//
#include <hip/hip_runtime.h>
#include <cmath>

#define B_   16
#define N_   1024
#define KV_  960
#define H_   2
#define LDP  1024                      // padded leading dim for all intermediates
#define PGE  ((size_t)1024 * 1024)    // padded slab stride (elements)

typedef __attribute__((ext_vector_type(8))) short     short8;
typedef __attribute__((ext_vector_type(8))) unsigned short ushort8;
typedef __attribute__((ext_vector_type(4))) unsigned short ushort4v;
typedef __attribute__((ext_vector_type(4))) float     f32x4;
typedef __attribute__((ext_vector_type(4))) float     float4v;
typedef __attribute__((ext_vector_type(2))) float     float2v;

__device__ inline ushort f2b(float f) {
    union { float f; unsigned u; } x; x.f = f;
    unsigned r = x.u + 0x7FFFu + ((x.u >> 16) & 1u);   // RNE
    return (ushort)(r >> 16);
}
__device__ inline float b2f(ushort u) {
    union { unsigned u; float f; } x; x.u = (unsigned)u << 16; return x.f;
}

// Bijective XCD-chunking swizzle (m204).
__device__ inline int xcd_swz(int orig, int nwg) {
    int q = nwg >> 3, r = nwg & 7;
    int xcd = orig & 7, idx = orig >> 3;
    return (xcd < r ? xcd * (q + 1) : r * (q + 1) + (xcd - r) * q) + idx;
}

// async global->LDS, 16B per lane (wave-uniform LDS base + lane*16)
__device__ inline void gload16(const ushort* g, ushort* l) {
    __builtin_amdgcn_global_load_lds(
        (const __attribute__((address_space(1))) void*)g,
        (__attribute__((address_space(3))) void*)l, 16, 0, 0);
}

// ---------------------------------------------------------------------------
// 256x128-tile bf16 MFMA GEMM, 512 threads (8 waves, 4Mx2N), BK=32.
// R16-verified structure (stage-ahead + one __syncthreads per K-step).
// NOW with runtime lda/ldb so exact-shape weight GEMMs (steps 2/7 big
// branches) can ride this path. A,B: k-contig rows. grid: gx=Nc/128, gy=M/256.
// C tuple is (C, ldc, sCb, sCh) — ldc is the ROW stride!
// ---------------------------------------------------------------------------
template<int HSUM, bool OUTF32, bool STATS>
__global__ __launch_bounds__(512)
void gemm256(int gx, int gy, int K, float alpha,
             const ushort* __restrict__ A, int lda, size_t sAb, size_t sAh,
             const ushort* __restrict__ Bm, int ldb, size_t sBb, size_t sBh,
             void* __restrict__ C, int ldc, size_t sCb, size_t sCh, int hsel,
             float2v* __restrict__ parts)
{
    __shared__ ushort As[2][256 * 32];   // 16 KB per buf
    __shared__ ushort Bs[2][128 * 32];   //  8 KB per buf
    const int wgid = xcd_swz(blockIdx.x, gridDim.x);
    const int xg = wgid % gx, rem = wgid / gx;
    const int yg = rem % gy, z = rem / gy;
    int b, h;
    if (hsel >= 0) { b = z; h = hsel; } else { b = z >> 1; h = z & 1; }
    const int m0 = yg * 256, n0 = xg * 128;
    const int t = threadIdx.x, lane = t & 63, wave = t >> 6;
    const int wr = wave >> 1, wc = wave & 1;          // 4 x 2 wave grid

    f32x4 acc[4][4];
#pragma unroll
    for (int i = 0; i < 4; ++i)
#pragma unroll
        for (int j = 0; j < 4; ++j) acc[i][j] = f32x4{0.f, 0.f, 0.f, 0.f};

    // staging decode: A = 1024 slots (2 reps), B = 512 slots (1 rep)
    int srowA[2], skofA[2];
#pragma unroll
    for (int rep = 0; rep < 2; ++rep) {
        int s = rep * 512 + t;
        srowA[rep] = s >> 2;
        skofA[rep] = ((s & 3) ^ ((srowA[rep] >> 1) & 3)) * 8;
    }
    const int srowB = t >> 2;
    const int skofB = ((t & 3) ^ ((srowB >> 1) & 3)) * 8;

    // ds_read offsets (swizzled), ushort units
    int aoff[4], boff[4];
#pragma unroll
    for (int i = 0; i < 4; ++i) {
        int ra = wr * 64 + i * 16 + (lane & 15);      // 0..255
        aoff[i] = ra * 32 + (((lane >> 4) ^ ((ra >> 1) & 3)) * 8);
        int rb = wc * 64 + i * 16 + (lane & 15);      // 0..127
        boff[i] = rb * 32 + (((lane >> 4) ^ ((rb >> 1) & 3)) * 8);
    }

    const int ksteps = K >> 5;          // K-steps per head slab
    const int total  = HSUM * ksteps;   // flattened (hh, k) steps

    auto stage = [&](int s, int buf) {  // 3 gload16 per thread
        const int hh = (HSUM == 2) ? (s >= ksteps ? 1 : 0) : h;
        const int k0 = ((HSUM == 2 && s >= ksteps) ? (s - ksteps) : s) << 5;
        const ushort* Ab = A + (size_t)b * sAb + (size_t)hh * sAh;
        const ushort* Bb = Bm + (size_t)b * sBb + (size_t)hh * sBh;
#pragma unroll
        for (int rep = 0; rep < 2; ++rep)
            gload16(Ab + (size_t)(m0 + srowA[rep]) * lda + k0 + skofA[rep],
                    &As[buf][(rep * 512 + t) * 8]);
        gload16(Bb + (size_t)(n0 + srowB) * ldb + k0 + skofB, &Bs[buf][t * 8]);
    };

    stage(0, 0);
    __syncthreads();                    // buf0 resident
    int cur = 0;
    for (int s = 0; s < total; ++s) {
        if (s + 1 < total) stage(s + 1, cur ^ 1);   // async prefetch
        short8 a[4], bv[4];
#pragma unroll
        for (int i = 0; i < 4; ++i) {
            a[i]  = *(const short8*)&As[cur][aoff[i]];
            bv[i] = *(const short8*)&Bs[cur][boff[i]];
        }
#pragma unroll
        for (int i = 0; i < 4; ++i)
#pragma unroll
            for (int j = 0; j < 4; ++j)
                acc[i][j] = __builtin_amdgcn_mfma_f32_16x16x32_bf16(a[i], bv[j], acc[i][j], 0, 0, 0);
        __syncthreads();                // drains prefetch; all reads of cur done
        cur ^= 1;
    }

    char* Cb = (char*)C + ((size_t)b * sCb + (size_t)h * sCh) * (OUTF32 ? 4 : 2);
#pragma unroll
    for (int i = 0; i < 4; ++i) {
        int row = m0 + wr * 64 + i * 16 + (lane >> 4) * 4;
#pragma unroll
        for (int q = 0; q < 4; ++q)
#pragma unroll
            for (int j = 0; j < 4; ++j) {
                int col = n0 + wc * 64 + j * 16 + (lane & 15);
                float v = alpha * acc[i][j][q];
                if (OUTF32) ((float*)Cb)[(size_t)(row + q) * ldc + col] = v;
                else        ((ushort*)Cb)[(size_t)(row + q) * ldc + col] = f2b(v);
            }
    }

    if constexpr (STATS) {
        float s1[4] = {0.f, 0.f, 0.f, 0.f}, s2[4] = {0.f, 0.f, 0.f, 0.f};
#pragma unroll
        for (int i = 0; i < 4; ++i) {
            int row = m0 + wr * 64 + i * 16 + (lane >> 4) * 4;
#pragma unroll
            for (int q = 0; q < 4; ++q) {
                int rr = row + q;
                if (rr >= KV_) continue;
                int br = rr < 64 ? 0 : rr < 192 ? 1 : rr < 448 ? 2 : 3;
#pragma unroll
                for (int j = 0; j < 4; ++j) {
                    int col = n0 + wc * 64 + j * 16 + (lane & 15);
                    if (col >= KV_) continue;
                    float v = alpha * acc[i][j][q];
                    s1[br] += v; s2[br] += v * v;
                }
            }
        }
#pragma unroll
        for (int br = 0; br < 4; ++br)
#pragma unroll
            for (int o = 32; o; o >>= 1) {
                s1[br] += __shfl_down(s1[br], o);
                s2[br] += __shfl_down(s2[br], o);
            }
        __shared__ float red[8][8];
        if (lane == 0) {
#pragma unroll
            for (int br = 0; br < 4; ++br) { red[wave][br] = s1[br]; red[wave][4 + br] = s2[br]; }
        }
        __syncthreads();
        if (t < 4) {   // t = branch
            float S1 = 0.f, S2 = 0.f;
#pragma unroll
            for (int w = 0; w < 8; ++w) { S1 += red[w][t]; S2 += red[w][4 + t]; }
            float2v r; r[0] = S1; r[1] = S2;
            parts[((size_t)z * 32 + yg * 8 + xg) * 4 + t] = r;
        }
    }
}

// ---------------------------------------------------------------------------
// 64x64 direct-staging helper (bf16 source)
// ---------------------------------------------------------------------------
__device__ inline void stage64b(const ushort* __restrict__ src, int ld, int r0, int k0,
                                ushort* __restrict__ lds, int t)
{
#pragma unroll
    for (int rep = 0; rep < 2; ++rep) {
        int idx = t + rep * 256;
        int rr = idx >> 3, kc = (idx & 7) << 3;
        *(ushort8*)&lds[rr * 72 + kc] =
            *(const ushort8*)(src + (size_t)(r0 + rr) * ld + (k0 + kc));
    }
}

// ---------------------------------------------------------------------------
// Step-2 SMALL branches only (c=64,128): Y rows = Wq_i[h] @ G2 cols.
// grid = NB*2*45 (15 + 30 tiles), block 256.
// ---------------------------------------------------------------------------
__global__ __launch_bounds__(256)
void ygemm(const ushort* __restrict__ W0, const ushort* __restrict__ W1,
           const ushort* __restrict__ G2, ushort* __restrict__ Y)
{
    __shared__ ushort As[64 * 72];
    __shared__ ushort Bs[64 * 72];
    const int wg = xcd_swz(blockIdx.x, gridDim.x);
    const int z = wg / 45, tl = wg % 45;
    const int b = z >> 1, h = z & 1;
    const int br = tl < 15 ? 0 : 1;
    const int loc = br == 0 ? tl : tl - 15;
    const int xg = loc % 15, yg = loc / 15;
    const int csz[2]  = {64, 128};
    const int coff[2] = {0, 64};
    const ushort* wp[2] = {W0, W1};
    const int c = csz[br];
    const ushort* A = wp[br] + (size_t)h * c * c;                      // [c][c]
    const ushort* B = G2 + (size_t)b * PGE + coff[br];                 // ldb=LDP
    ushort* Cp = Y + (size_t)b * 2 * PGE + (size_t)h * PGE + (size_t)coff[br] * LDP;
    const int m0 = yg * 64, n0 = xg * 64;
    const int t = threadIdx.x, lane = t & 63, wave = t >> 6;
    const int wr = wave >> 1, wc = wave & 1;

    f32x4 z4 = {0.f, 0.f, 0.f, 0.f};
    f32x4 acc[2][2]; acc[0][0] = z4; acc[0][1] = z4; acc[1][0] = z4; acc[1][1] = z4;

    for (int k0 = 0; k0 < c; k0 += 64) {
        stage64b(A, c, m0, k0, As, t);
        stage64b(B, LDP, n0, k0, Bs, t);
        __syncthreads();
        const int ar = wr * 32 + (lane & 15);
        const int brw = wc * 32 + (lane & 15);
        const int kg = (lane >> 4) * 8;
#pragma unroll
        for (int ks = 0; ks < 2; ++ks) {
            short8 a0 = *(const short8*)&As[(ar)      * 72 + ks * 32 + kg];
            short8 a1 = *(const short8*)&As[(ar + 16) * 72 + ks * 32 + kg];
            short8 b0 = *(const short8*)&Bs[(brw)      * 72 + ks * 32 + kg];
            short8 b1 = *(const short8*)&Bs[(brw + 16) * 72 + ks * 32 + kg];
            acc[0][0] = __builtin_amdgcn_mfma_f32_16x16x32_bf16(a0, b0, acc[0][0], 0, 0, 0);
            acc[0][1] = __builtin_amdgcn_mfma_f32_16x16x32_bf16(a0, b1, acc[0][1], 0, 0, 0);
            acc[1][0] = __builtin_amdgcn_mfma_f32_16x16x32_bf16(a1, b0, acc[1][0], 0, 0, 0);
            acc[1][1] = __builtin_amdgcn_mfma_f32_16x16x32_bf16(a1, b1, acc[1][1], 0, 0, 0);
        }
        __syncthreads();
    }
#pragma unroll
    for (int i = 0; i < 2; ++i)
#pragma unroll
        for (int q = 0; q < 4; ++q) {
            int row = m0 + wr * 32 + i * 16 + (lane >> 4) * 4 + q;
#pragma unroll
            for (int j = 0; j < 2; ++j) {
                int col = n0 + wc * 32 + j * 16 + (lane & 15);
                Cp[(size_t)row * LDP + col] = f2b(acc[i][j][q]);
            }
        }
}

// ---------------------------------------------------------------------------
// Step-7 SMALL branches only (c=64,128): out cols = ctx_i @ Wo_i^T (f32).
// grid = NB*48 (16 + 32 tiles), block 256.
// ---------------------------------------------------------------------------
__global__ __launch_bounds__(256)
void ogemm(const ushort* __restrict__ ctx,
           const ushort* __restrict__ O0, const ushort* __restrict__ O1,
           float* __restrict__ out)
{
    __shared__ ushort As[64 * 72];
    __shared__ ushort Bs[64 * 72];
    const int wg = xcd_swz(blockIdx.x, gridDim.x);
    const int b = wg / 48, tl = wg % 48;
    const int br = tl < 16 ? 0 : 1;
    const int loc = br == 0 ? tl : tl - 16;
    const int csz[2]  = {64, 128};
    const int coff[2] = {0, 64};
    const ushort* op[2] = {O0, O1};
    const int c = csz[br];
    const int gxi = c / 64;
    const int xg = loc % gxi, yg = loc / gxi;   // yg 0..15
    const ushort* A = ctx + (size_t)b * PGE + coff[br];   // lda=LDP
    const ushort* B = op[br];                             // ldb=c
    float* Cf = out + (size_t)b * ((size_t)N_ * KV_) + coff[br];  // ldc=KV_
    const int m0 = yg * 64, n0 = xg * 64;
    const int t = threadIdx.x, lane = t & 63, wave = t >> 6;
    const int wr = wave >> 1, wc = wave & 1;

    f32x4 z4 = {0.f, 0.f, 0.f, 0.f};
    f32x4 acc[2][2]; acc[0][0] = z4; acc[0][1] = z4; acc[1][0] = z4; acc[1][1] = z4;

    for (int k0 = 0; k0 < c; k0 += 64) {
        stage64b(A, LDP, m0, k0, As, t);
        stage64b(B, c, n0, k0, Bs, t);
        __syncthreads();
        const int ar = wr * 32 + (lane & 15);
        const int brw = wc * 32 + (lane & 15);
        const int kg = (lane >> 4) * 8;
#pragma unroll
        for (int ks = 0; ks < 2; ++ks) {
            short8 a0 = *(const short8*)&As[(ar)      * 72 + ks * 32 + kg];
            short8 a1 = *(const short8*)&As[(ar + 16) * 72 + ks * 32 + kg];
            short8 b0 = *(const short8*)&Bs[(brw)      * 72 + ks * 32 + kg];
            short8 b1 = *(const short8*)&Bs[(brw + 16) * 72 + ks * 32 + kg];
            acc[0][0] = __builtin_amdgcn_mfma_f32_16x16x32_bf16(a0, b0, acc[0][0], 0, 0, 0);
            acc[0][1] = __builtin_amdgcn_mfma_f32_16x16x32_bf16(a0, b1, acc[0][1], 0, 0, 0);
            acc[1][0] = __builtin_amdgcn_mfma_f32_16x16x32_bf16(a1, b0, acc[1][0], 0, 0, 0);
            acc[1][1] = __builtin_amdgcn_mfma_f32_16x16x32_bf16(a1, b1, acc[1][1], 0, 0, 0);
        }
        __syncthreads();
    }
#pragma unroll
    for (int i = 0; i < 2; ++i)
#pragma unroll
        for (int q = 0; q < 4; ++q) {
            int row = m0 + wr * 32 + i * 16 + (lane >> 4) * 4 + q;
#pragma unroll
            for (int j = 0; j < 2; ++j) {
                int col = n0 + wc * 32 + j * 16 + (lane & 15);
                Cf[(size_t)row * KV_ + col] = acc[i][j][q];
            }
        }
}

// ---------------------------------------------------------------------------
// Batched weight convert: 8 segments (Wq x4, Wo x4), one launch.
// ---------------------------------------------------------------------------
struct WSeg { const float* s; ushort* d; unsigned n; };
struct WcvtA { WSeg seg[8]; };
__global__ __launch_bounds__(256)
void wcvt(WcvtA a)
{
    WSeg sg = a.seg[blockIdx.y];
    for (size_t i = ((size_t)blockIdx.x * 256 + threadIdx.x) * 4; i < sg.n;
         i += (size_t)gridDim.x * 1024) {
        float4v f = *(const float4v*)(sg.s + i);
        ushort4v v;
        v[0] = f2b(f[0]); v[1] = f2b(f[1]); v[2] = f2b(f[2]); v[3] = f2b(f[3]);
        *(ushort4v*)(sg.d + i) = v;
    }
}

// f32 (ld=sld) -> bf16 (ld=dld) re-strided convert; cols=960 (120 x ushort8)
__global__ __launch_bounds__(256)
void cvt_ld(const float* __restrict__ src, int sld, size_t sYsrc,
            ushort* __restrict__ dst, int dld, size_t sYdst, int total_chunks)
{
    const float* s0 = src + (size_t)blockIdx.y * sYsrc;
    ushort* d0 = dst + (size_t)blockIdx.y * sYdst;
    for (int ch = blockIdx.x * 256 + threadIdx.x; ch < total_chunks;
         ch += gridDim.x * 256) {
        int row = ch / 120, c = (ch % 120) * 8;
        const float* s = s0 + (size_t)row * sld + c;
        float4v f0 = *(const float4v*)s;
        float4v f1 = *(const float4v*)(s + 4);
        ushort8 v;
        v[0] = f2b(f0[0]); v[1] = f2b(f0[1]); v[2] = f2b(f0[2]); v[3] = f2b(f0[3]);
        v[4] = f2b(f1[0]); v[5] = f2b(f1[1]); v[6] = f2b(f1[2]); v[7] = f2b(f1[3]);
        *(ushort8*)(d0 + (size_t)row * dld + c) = v;
    }
}

// ---------------------------------------------------------------------------
// Generic f32 [R][C] -> bf16 [C][R] tile transpose+convert (used for WvT).
// ---------------------------------------------------------------------------
__global__ __launch_bounds__(256)
void tposecvt(const float* __restrict__ src, size_t sSrc, int sld,
              ushort* __restrict__ dst, size_t sDst, int dld)
{
    __shared__ ushort tile[32][33];
    const float* s = src + (size_t)blockIdx.z * sSrc;
    ushort* d = dst + (size_t)blockIdx.z * sDst;
    int c0 = blockIdx.x * 32, r0 = blockIdx.y * 32;
    for (int i = threadIdx.y; i < 32; i += 8)
        tile[i][threadIdx.x] = f2b(s[(size_t)(r0 + i) * sld + c0 + threadIdx.x]);
    __syncthreads();
    for (int i = threadIdx.y; i < 32; i += 8)
        d[(size_t)(c0 + i) * dld + r0 + threadIdx.x] = tile[threadIdx.x][i];
}

// ---------------------------------------------------------------------------
// emb_all f32 [n=1024][m=960] -> EA bf16 [n][LDP] AND EAT bf16 [m][LDP] (=^T)
// 64x64 tiles, block (64,4), f32 LDS [64][65]. grid (15, 16, NB).
// ---------------------------------------------------------------------------
__global__ __launch_bounds__(256)
void dualcvt(const float* __restrict__ src, ushort* __restrict__ ea, size_t sEA,
             ushort* __restrict__ eat, size_t sEAT)
{
    __shared__ float tile[64][65];
    const float* s = src + (size_t)blockIdx.z * ((size_t)N_ * KV_);
    ushort* pea  = ea  + (size_t)blockIdx.z * sEA;
    ushort* peat = eat + (size_t)blockIdx.z * sEAT;
    int m0 = blockIdx.x * 64, n0 = blockIdx.y * 64;
    int tx = threadIdx.x, ty = threadIdx.y;
    for (int i = ty; i < 64; i += 4) {
        float v = s[(size_t)(n0 + i) * KV_ + m0 + tx];
        tile[i][tx] = v;
        pea[(size_t)(n0 + i) * LDP + m0 + tx] = f2b(v);
    }
    __syncthreads();
    for (int i = ty; i < 64; i += 4)
        peat[(size_t)(m0 + i) * LDP + n0 + tx] = f2b(tile[tx][i]);
}

// ---------------------------------------------------------------------------
// Batched emb_cat transpose: embT[p][n], 64x64 tiles, f32 LDS.
// grid (15, 16, NB), block (64,4). x-tile decode: 1,2,4,8 tiles per branch.
// ---------------------------------------------------------------------------
__global__ __launch_bounds__(256)
void embtall(const float* __restrict__ e0, const float* __restrict__ e1,
             const float* __restrict__ e2, const float* __restrict__ e3,
             ushort* __restrict__ embT)
{
    __shared__ float tile[64][65];
    const int xt = blockIdx.x;
    const int br = xt < 1 ? 0 : xt < 3 ? 1 : xt < 7 ? 2 : 3;
    const int st = br == 0 ? 0 : br == 1 ? 1 : br == 2 ? 3 : 7;
    const int loc = xt - st;
    const int csz[4]  = {64, 128, 256, 512};
    const int coff[4] = {0, 64, 192, 448};
    const float* ep[4] = {e0, e1, e2, e3};
    const int c = csz[br];
    const float* s = ep[br] + (size_t)blockIdx.z * ((size_t)N_ * c);
    ushort* d = embT + (size_t)blockIdx.z * (2 * PGE) + (size_t)coff[br] * LDP;
    int c0 = loc * 64, r0 = blockIdx.y * 64;
    int tx = threadIdx.x, ty = threadIdx.y;
    for (int i = ty; i < 64; i += 4)
        tile[i][tx] = s[(size_t)(r0 + i) * c + c0 + tx];
    __syncthreads();
    for (int i = ty; i < 64; i += 4)
        d[(size_t)(c0 + i) * LDP + r0 + tx] = f2b(tile[tx][i]);
}

// ---------------------------------------------------------------------------
// Final stats from per-tile partials (fixed order => deterministic).
// grid NB*H*4 (z = bh*4+br), block 64. 32 tiles per (b,h) slab.
// ---------------------------------------------------------------------------
__global__ __launch_bounds__(64)
void normstats2b(const float2v* __restrict__ parts, float* __restrict__ stats)
{
    const int z = blockIdx.x;
    const int bh = z >> 2, br = z & 3;
    const int csz[4] = {64, 128, 256, 512};
    if (threadIdx.x == 0) {
        float s = 0.f, s2 = 0.f;
        const float2v* p = parts + (size_t)bh * 128 + br;
        for (int t = 0; t < 32; ++t) {
            float2v r = p[t * 4];
            s += r[0]; s2 += r[1];
        }
        const float inv_cnt = 1.0f / (float)(csz[br] * KV_);
        float mu  = s * inv_cnt;
        float var = s2 * inv_cnt - mu * mu;
        stats[2 * z]     = mu;
        stats[2 * z + 1] = rsqrtf(var + 1e-5f);
    }
}

// ---------------------------------------------------------------------------
// Row softmax, in place on bf16 scores (real 960 cols of LDP-stride rows).
// ---------------------------------------------------------------------------
__global__ __launch_bounds__(256)
void psoftmax(ushort* __restrict__ S, const float* __restrict__ stats)
{
    const int r  = blockIdx.x;
    const int bh  = r / KV_;
    const int row = r % KV_;
    const int br  = (row < 64) ? 0 : (row < 192) ? 1 : (row < 448) ? 2 : 3;
    const float mu = stats[2 * (bh * 4 + br)];
    const float rs = stats[2 * (bh * 4 + br) + 1];
    ushort* p = S + (size_t)bh * PGE + (size_t)row * LDP;

    const int t = threadIdx.x;
    float x[4];
    float mx = -1e30f;
#pragma unroll
    for (int i = 0; i < 4; ++i) {
        int idx = t + i * 256;
        x[i] = (idx < KV_) ? (b2f(p[idx]) - mu) * rs : -1e30f;
        mx = fmaxf(mx, x[i]);
    }
#pragma unroll
    for (int o = 1; o < 64; o <<= 1) mx = fmaxf(mx, __shfl_xor(mx, o));
    __shared__ float wmax[4], wsum[4];
    int w = t >> 6, l = t & 63;
    if (l == 0) wmax[w] = mx;
    __syncthreads();
    mx = fmaxf(fmaxf(wmax[0], wmax[1]), fmaxf(wmax[2], wmax[3]));

    float s = 0.f;
#pragma unroll
    for (int i = 0; i < 4; ++i) {
        x[i] = expf(x[i] - mx);
        s += x[i];
    }
#pragma unroll
    for (int o = 1; o < 64; o <<= 1) s += __shfl_xor(s, o);
    if (l == 0) wsum[w] = s;
    __syncthreads();
    s = wsum[0] + wsum[1] + wsum[2] + wsum[3];
    float inv = 1.0f / s;
#pragma unroll
    for (int i = 0; i < 4; ++i) {
        int idx = t + i * 256;
        if (idx < KV_) p[idx] = f2b(x[i] * inv);
    }
}

// ---------------------------------------------------------------------------
extern "C" void kernel_launch(void* const* d_in, const int* in_sizes, int n_in,
                              void* d_out, int out_size, void* d_ws, size_t ws_size,
                              hipStream_t stream)
{
    const float* emb[4] = {(const float*)d_in[0], (const float*)d_in[1],
                           (const float*)d_in[2], (const float*)d_in[3]};
    const float* emb_all = (const float*)d_in[4];
    const float* Wq[4] = {(const float*)d_in[5], (const float*)d_in[7],
                          (const float*)d_in[9], (const float*)d_in[11]};
    const float* Wo[4] = {(const float*)d_in[6], (const float*)d_in[8],
                          (const float*)d_in[10], (const float*)d_in[12]};
    const float* Wk = (const float*)d_in[13];
    const float* Wv = (const float*)d_in[14];
    float* out = (float*)d_out;

    const int c_sz[4]  = {64, 128, 256, 512};

    const size_t BN  = (size_t)N_ * KV_;     // 983040
    const size_t GE9 = (size_t)KV_ * KV_;    // 921600
    const float SCALE = 0.03227486121839514f;  // 1/sqrt(960)

    char* wsp = (char*)d_ws;
    size_t off = 0;
    auto alloc = [&](size_t bytes) -> char* {
        off = (off + 255) & ~(size_t)255;
        char* p = wsp + off;
        off += bytes;
        return p;
    };

    // Static: bf16 weights
    ushort* WqB[4]; ushort* WoB[4];
    for (int i = 0; i < 4; ++i) WqB[i] = (ushort*)alloc((size_t)2 * c_sz[i] * c_sz[i] * 2);
    for (int i = 0; i < 4; ++i) WoB[i] = (ushort*)alloc((size_t)c_sz[i] * c_sz[i] * 2);
    ushort* WkB = (ushort*)alloc(2 * PGE * 2);   // [2][1024][LDP]
    ushort* WvT = (ushort*)alloc(2 * PGE * 2);   // [2][m][k] bf16, LD=LDP

    {
        WcvtA a;
        for (int i = 0; i < 4; ++i) {
            a.seg[i]     = { Wq[i], WqB[i], (unsigned)(2 * c_sz[i] * c_sz[i]) };
            a.seg[4 + i] = { Wo[i], WoB[i], (unsigned)(c_sz[i] * c_sz[i]) };
        }
        wcvt<<<dim3(64, 8), 256, 0, stream>>>(a);
    }
    cvt_ld<<<dim3(450, 2), 256, 0, stream>>>(Wk, KV_, GE9, WkB, LDP, PGE, 960 * 120);
    tposecvt<<<dim3(30, 30, 2), dim3(32, 8), 0, stream>>>(Wv, GE9, KV_, WvT, PGE, LDP);

    // Per-batch slots with aliasing: slotA PGE (G2/ctx) ; Y 2*PGE (embT->Y->R) ;
    // Sc 2*PGE (EAT -> scores/P) ; EA PGE  => 6*PGE*2B = 12 MB/batch
    const size_t perB = 6 * PGE * 2;
    size_t statik = (off + 255) & ~(size_t)255;
    int NB = 16;
    while (NB > 1 && statik + (size_t)NB * perB + 262144 > ws_size) NB >>= 1;

    ushort* slotA = (ushort*)alloc((size_t)NB * PGE * 2);       // G2 / ctx
    ushort* Y     = (ushort*)alloc((size_t)NB * 2 * PGE * 2);   // embT -> Y -> R
    ushort* Sc    = (ushort*)alloc((size_t)NB * 2 * PGE * 2);   // EAT -> scores/P
    ushort* EA    = (ushort*)alloc((size_t)NB * PGE * 2);       // emb_all bf16 [n][m]
    float*  stats = (float*) alloc((size_t)NB * 2 * 4 * 2 * 4);
    float2v* parts = (float2v*)alloc((size_t)NB * 2 * 64 * 4 * 8);
    ushort* EAT  = Sc;   // [NB][1024][LDP], batch stride 2*PGE — dead after step 1
    ushort* embT = Y;    // [NB][1024][LDP], batch stride 2*PGE — dead after step 1
    ushort* R    = Y;    // [NB][1024][LDP], batch stride 2*PGE after step 5

    for (int b0 = 0; b0 < B_; b0 += NB) {
        // 0) EA [n][m] + EAT [m][n] one pass ; embT [p][n] (batched, 64-wide)
        dualcvt<<<dim3(15, 16, NB), dim3(64, 4), 0, stream>>>(
            emb_all + (size_t)b0 * BN, EA, PGE, EAT, 2 * PGE);
        embtall<<<dim3(15, 16, NB), dim3(64, 4), 0, stream>>>(
            emb[0] + (size_t)b0 * N_ * 64,  emb[1] + (size_t)b0 * N_ * 128,
            emb[2] + (size_t)b0 * N_ * 256, emb[3] + (size_t)b0 * N_ * 512,
            embT);

        // 1) G2[m,p] = sum_n EA[n,m]*emb_cat[n,p]  (256x128-path, K=1024)
        gemm256<1, false, false><<<dim3(8 * 4 * NB), 512, 0, stream>>>(
            8, 4, N_, 1.0f,
            EAT, LDP, 2 * PGE, 0,
            embT, LDP, 2 * PGE, 0,
            slotA, LDP, PGE, 0, /*hsel=*/0, nullptr);

        // 2) Y = Wq @ G2:
        //   c=512 branch on 256x128 path (M=512, N=960+pad, K=512)
        gemm256<1, false, false><<<dim3(8 * 2 * NB * H_), 512, 0, stream>>>(
            8, 2, 512, 1.0f,
            WqB[3], 512, 0, (size_t)512 * 512,
            slotA + 448, LDP, PGE, 0,
            Y + (size_t)448 * LDP, LDP, 2 * PGE, PGE, /*hsel=*/-1, nullptr);
        //   c=256 branch (M=256, K=256)
        gemm256<1, false, false><<<dim3(8 * 1 * NB * H_), 512, 0, stream>>>(
            8, 1, 256, 1.0f,
            WqB[2], 256, 0, (size_t)256 * 256,
            slotA + 192, LDP, PGE, 0,
            Y + (size_t)192 * LDP, LDP, 2 * PGE, PGE, /*hsel=*/-1, nullptr);
        //   c=64,128 branches on 64-tile path
        ygemm<<<dim3(NB * 2 * 45), 256, 0, stream>>>(WqB[0], WqB[1], slotA, Y);

        // 3) scores bf16 = SCALE * Y @ Wk[h]^T  + fused stats partials
        gemm256<1, false, true><<<dim3(8 * 4 * NB * H_), 512, 0, stream>>>(
            8, 4, KV_, SCALE,
            Y, LDP, 2 * PGE, PGE,
            WkB, LDP, 0, PGE,
            Sc, LDP, 2 * PGE, PGE, /*hsel=*/-1, parts);

        // 4) finalize stats + in-place softmax on Sc
        normstats2b<<<NB * H_ * 4, 64, 0, stream>>>(parts, stats);
        psoftmax<<<NB * H_ * KV_, 256, 0, stream>>>(Sc, stats);

        // 5) R[p,m] = sum_h P[b,h] @ WvT[h] rows  (256x128-path, HSUM=2)
        gemm256<2, false, false><<<dim3(8 * 4 * NB), 512, 0, stream>>>(
            8, 4, KV_, 1.0f,
            Sc, LDP, 2 * PGE, PGE,
            WvT, LDP, 0, PGE,
            R, LDP, 2 * PGE, 0, /*hsel=*/0, nullptr);

        // 6) ctx[n,p] = 0.5 * EA @ R^T  (256x128-path)
        gemm256<1, false, false><<<dim3(8 * 4 * NB), 512, 0, stream>>>(
            8, 4, KV_, 0.5f,
            EA, LDP, PGE, 0,
            R, LDP, 2 * PGE, 0,
            slotA, LDP, PGE, 0, /*hsel=*/0, nullptr);

        // 7) out = ctx @ Wo^T:
        //   c=512 branch (M=1024, N=512, K=512), f32 out
        gemm256<1, true, false><<<dim3(4 * 4 * NB), 512, 0, stream>>>(
            4, 4, 512, 1.0f,
            slotA + 448, LDP, PGE, 0,
            WoB[3], 512, 0, 0,
            out + (size_t)b0 * BN + 448, KV_, BN, 0, /*hsel=*/0, nullptr);
        //   c=256 branch (N=256, K=256)
        gemm256<1, true, false><<<dim3(2 * 4 * NB), 512, 0, stream>>>(
            2, 4, 256, 1.0f,
            slotA + 192, LDP, PGE, 0,
            WoB[2], 256, 0, 0,
            out + (size_t)b0 * BN + 192, KV_, BN, 0, /*hsel=*/0, nullptr);
        //   c=64,128 branches on 64-tile path
        ogemm<<<dim3(NB * 48), 256, 0, stream>>>(
            slotA, WoB[0], WoB[1], out + (size_t)b0 * BN);
    }
}

// Round 18
// 433.240 us; speedup vs baseline: 1.0278x; 1.0278x over previous
//
#include <hip/hip_runtime.h>
#include <cmath>

#define B_   16
#define N_   1024
#define KV_  960
#define H_   2
#define LDP  1024                      // padded leading dim for all intermediates
#define PGE  ((size_t)1024 * 1024)    // padded slab stride (elements)

typedef __attribute__((ext_vector_type(8))) short     short8;
typedef __attribute__((ext_vector_type(8))) unsigned short ushort8;
typedef __attribute__((ext_vector_type(4))) unsigned short ushort4v;
typedef __attribute__((ext_vector_type(4))) float     f32x4;
typedef __attribute__((ext_vector_type(4))) float     float4v;
typedef __attribute__((ext_vector_type(2))) float     float2v;

__device__ inline ushort f2b(float f) {
    union { float f; unsigned u; } x; x.f = f;
    unsigned r = x.u + 0x7FFFu + ((x.u >> 16) & 1u);   // RNE
    return (ushort)(r >> 16);
}
__device__ inline float b2f(ushort u) {
    union { unsigned u; float f; } x; x.u = (unsigned)u << 16; return x.f;
}

// Bijective XCD-chunking swizzle (m204).
__device__ inline int xcd_swz(int orig, int nwg) {
    int q = nwg >> 3, r = nwg & 7;
    int xcd = orig & 7, idx = orig >> 3;
    return (xcd < r ? xcd * (q + 1) : r * (q + 1) + (xcd - r) * q) + idx;
}

// async global->LDS, 16B per lane (wave-uniform LDS base + lane*16)
__device__ inline void gload16(const ushort* g, ushort* l) {
    __builtin_amdgcn_global_load_lds(
        (const __attribute__((address_space(1))) void*)g,
        (__attribute__((address_space(3))) void*)l, 16, 0, 0);
}

// ---------------------------------------------------------------------------
// 256x128-tile bf16 MFMA GEMM, 512 threads (8 waves, 4Mx2N), BK=32.
// R16-verified structure (stage-ahead + one __syncthreads per K-step,
// runtime cur flip, chunk-XOR swizzle, 0 bank conflicts, 443 us total).
// A,B: [*][LDP] bf16 k-contig. C tuple is (C, ldc, sCb, sCh) — ldc ROW stride!
// STATS: fused per-block masked per-branch (sum,sumsq) partials.
// grid decode: gx = Nc/128, gy = M/256.
// ---------------------------------------------------------------------------
template<int HSUM, bool OUTF32, bool STATS>
__global__ __launch_bounds__(512)
void gemm256(int gx, int gy, int K, float alpha,
             const ushort* __restrict__ A, size_t sAb, size_t sAh,
             const ushort* __restrict__ Bm, size_t sBb, size_t sBh,
             void* __restrict__ C, int ldc, size_t sCb, size_t sCh, int hsel,
             float2v* __restrict__ parts)
{
    __shared__ ushort As[2][256 * 32];   // 16 KB per buf
    __shared__ ushort Bs[2][128 * 32];   //  8 KB per buf
    const int wgid = xcd_swz(blockIdx.x, gridDim.x);
    const int xg = wgid % gx, rem = wgid / gx;
    const int yg = rem % gy, z = rem / gy;
    int b, h;
    if (hsel >= 0) { b = z; h = hsel; } else { b = z >> 1; h = z & 1; }
    const int m0 = yg * 256, n0 = xg * 128;
    const int t = threadIdx.x, lane = t & 63, wave = t >> 6;
    const int wr = wave >> 1, wc = wave & 1;          // 4 x 2 wave grid

    f32x4 acc[4][4];
#pragma unroll
    for (int i = 0; i < 4; ++i)
#pragma unroll
        for (int j = 0; j < 4; ++j) acc[i][j] = f32x4{0.f, 0.f, 0.f, 0.f};

    // staging decode: A = 1024 slots (2 reps), B = 512 slots (1 rep)
    int srowA[2], skofA[2];
#pragma unroll
    for (int rep = 0; rep < 2; ++rep) {
        int s = rep * 512 + t;
        srowA[rep] = s >> 2;
        skofA[rep] = ((s & 3) ^ ((srowA[rep] >> 1) & 3)) * 8;
    }
    const int srowB = t >> 2;
    const int skofB = ((t & 3) ^ ((srowB >> 1) & 3)) * 8;

    // ds_read offsets (swizzled), ushort units — identical scheme to gemm128
    int aoff[4], boff[4];
#pragma unroll
    for (int i = 0; i < 4; ++i) {
        int ra = wr * 64 + i * 16 + (lane & 15);      // 0..255
        aoff[i] = ra * 32 + (((lane >> 4) ^ ((ra >> 1) & 3)) * 8);
        int rb = wc * 64 + i * 16 + (lane & 15);      // 0..127
        boff[i] = rb * 32 + (((lane >> 4) ^ ((rb >> 1) & 3)) * 8);
    }

    const int ksteps = K >> 5;          // K-steps per head slab
    const int total  = HSUM * ksteps;   // flattened (hh, k) steps

    auto stage = [&](int s, int buf) {  // 3 gload16 per thread
        const int hh = (HSUM == 2) ? (s >= ksteps ? 1 : 0) : h;
        const int k0 = ((HSUM == 2 && s >= ksteps) ? (s - ksteps) : s) << 5;
        const ushort* Ab = A + (size_t)b * sAb + (size_t)hh * sAh;
        const ushort* Bb = Bm + (size_t)b * sBb + (size_t)hh * sBh;
#pragma unroll
        for (int rep = 0; rep < 2; ++rep)
            gload16(Ab + (size_t)(m0 + srowA[rep]) * LDP + k0 + skofA[rep],
                    &As[buf][(rep * 512 + t) * 8]);
        gload16(Bb + (size_t)(n0 + srowB) * LDP + k0 + skofB, &Bs[buf][t * 8]);
    };

    stage(0, 0);
    __syncthreads();                    // buf0 resident
    int cur = 0;
    for (int s = 0; s < total; ++s) {
        if (s + 1 < total) stage(s + 1, cur ^ 1);   // async prefetch
        short8 a[4], bv[4];
#pragma unroll
        for (int i = 0; i < 4; ++i) {
            a[i]  = *(const short8*)&As[cur][aoff[i]];
            bv[i] = *(const short8*)&Bs[cur][boff[i]];
        }
#pragma unroll
        for (int i = 0; i < 4; ++i)
#pragma unroll
            for (int j = 0; j < 4; ++j)
                acc[i][j] = __builtin_amdgcn_mfma_f32_16x16x32_bf16(a[i], bv[j], acc[i][j], 0, 0, 0);
        __syncthreads();                // drains prefetch; all reads of cur done
        cur ^= 1;
    }

    char* Cb = (char*)C + ((size_t)b * sCb + (size_t)h * sCh) * (OUTF32 ? 4 : 2);
#pragma unroll
    for (int i = 0; i < 4; ++i) {
        int row = m0 + wr * 64 + i * 16 + (lane >> 4) * 4;
#pragma unroll
        for (int q = 0; q < 4; ++q)
#pragma unroll
            for (int j = 0; j < 4; ++j) {
                int col = n0 + wc * 64 + j * 16 + (lane & 15);
                float v = alpha * acc[i][j][q];
                if (OUTF32) ((float*)Cb)[(size_t)(row + q) * ldc + col] = v;
                else        ((ushort*)Cb)[(size_t)(row + q) * ldc + col] = f2b(v);
            }
    }

    if constexpr (STATS) {
        float s1[4] = {0.f, 0.f, 0.f, 0.f}, s2[4] = {0.f, 0.f, 0.f, 0.f};
#pragma unroll
        for (int i = 0; i < 4; ++i) {
            int row = m0 + wr * 64 + i * 16 + (lane >> 4) * 4;
#pragma unroll
            for (int q = 0; q < 4; ++q) {
                int rr = row + q;
                if (rr >= KV_) continue;
                int br = rr < 64 ? 0 : rr < 192 ? 1 : rr < 448 ? 2 : 3;
#pragma unroll
                for (int j = 0; j < 4; ++j) {
                    int col = n0 + wc * 64 + j * 16 + (lane & 15);
                    if (col >= KV_) continue;
                    float v = alpha * acc[i][j][q];
                    s1[br] += v; s2[br] += v * v;
                }
            }
        }
#pragma unroll
        for (int br = 0; br < 4; ++br)
#pragma unroll
            for (int o = 32; o; o >>= 1) {
                s1[br] += __shfl_down(s1[br], o);
                s2[br] += __shfl_down(s2[br], o);
            }
        __shared__ float red[8][8];
        if (lane == 0) {
#pragma unroll
            for (int br = 0; br < 4; ++br) { red[wave][br] = s1[br]; red[wave][4 + br] = s2[br]; }
        }
        __syncthreads();
        if (t < 4) {   // t = branch
            float S1 = 0.f, S2 = 0.f;
#pragma unroll
            for (int w = 0; w < 8; ++w) { S1 += red[w][t]; S2 += red[w][4 + t]; }
            float2v r; r[0] = S1; r[1] = S2;
            // tiles per slab = gy*gx = 32 ; tile id = yg*gx + xg
            parts[((size_t)z * 32 + yg * 8 + xg) * 4 + t] = r;
        }
    }
}

// ---------------------------------------------------------------------------
// 64x64 direct-staging helper (bf16 source)
// ---------------------------------------------------------------------------
__device__ inline void stage64b(const ushort* __restrict__ src, int ld, int r0, int k0,
                                ushort* __restrict__ lds, int t)
{
#pragma unroll
    for (int rep = 0; rep < 2; ++rep) {
        int idx = t + rep * 256;
        int rr = idx >> 3, kc = (idx & 7) << 3;
        *(ushort8*)&lds[rr * 72 + kc] =
            *(const ushort8*)(src + (size_t)(r0 + rr) * ld + (k0 + kc));
    }
}

// ---------------------------------------------------------------------------
// Batched step-2: Y rows c_off.. = Wq_i[h] @ G2 cols c_off..
// grid = NB*2*225 (tile decode: 15,30,60,120 tiles per branch), block 256.
// ---------------------------------------------------------------------------
__global__ __launch_bounds__(256)
void ygemm(const ushort* __restrict__ W0, const ushort* __restrict__ W1,
           const ushort* __restrict__ W2, const ushort* __restrict__ W3,
           const ushort* __restrict__ G2, ushort* __restrict__ Y)
{
    __shared__ ushort As[64 * 72];
    __shared__ ushort Bs[64 * 72];
    const int wg = xcd_swz(blockIdx.x, gridDim.x);
    const int z = wg / 225, tl = wg % 225;
    const int b = z >> 1, h = z & 1;
    const int br = tl < 15 ? 0 : tl < 45 ? 1 : tl < 105 ? 2 : 3;
    const int st = br == 0 ? 0 : br == 1 ? 15 : br == 2 ? 45 : 105;
    const int loc = tl - st;
    const int xg = loc % 15, yg = loc / 15;
    const int csz[4]  = {64, 128, 256, 512};
    const int coff[4] = {0, 64, 192, 448};
    const ushort* wp[4] = {W0, W1, W2, W3};
    const int c = csz[br];
    const ushort* A = wp[br] + (size_t)h * c * c;                      // [c][c]
    const ushort* B = G2 + (size_t)b * PGE + coff[br];                 // ldb=LDP
    ushort* Cp = Y + (size_t)b * 2 * PGE + (size_t)h * PGE + (size_t)coff[br] * LDP;
    const int m0 = yg * 64, n0 = xg * 64;
    const int t = threadIdx.x, lane = t & 63, wave = t >> 6;
    const int wr = wave >> 1, wc = wave & 1;

    f32x4 z4 = {0.f, 0.f, 0.f, 0.f};
    f32x4 acc[2][2]; acc[0][0] = z4; acc[0][1] = z4; acc[1][0] = z4; acc[1][1] = z4;

    for (int k0 = 0; k0 < c; k0 += 64) {
        stage64b(A, c, m0, k0, As, t);
        stage64b(B, LDP, n0, k0, Bs, t);
        __syncthreads();
        const int ar = wr * 32 + (lane & 15);
        const int brw = wc * 32 + (lane & 15);
        const int kg = (lane >> 4) * 8;
#pragma unroll
        for (int ks = 0; ks < 2; ++ks) {
            short8 a0 = *(const short8*)&As[(ar)      * 72 + ks * 32 + kg];
            short8 a1 = *(const short8*)&As[(ar + 16) * 72 + ks * 32 + kg];
            short8 b0 = *(const short8*)&Bs[(brw)      * 72 + ks * 32 + kg];
            short8 b1 = *(const short8*)&Bs[(brw + 16) * 72 + ks * 32 + kg];
            acc[0][0] = __builtin_amdgcn_mfma_f32_16x16x32_bf16(a0, b0, acc[0][0], 0, 0, 0);
            acc[0][1] = __builtin_amdgcn_mfma_f32_16x16x32_bf16(a0, b1, acc[0][1], 0, 0, 0);
            acc[1][0] = __builtin_amdgcn_mfma_f32_16x16x32_bf16(a1, b0, acc[1][0], 0, 0, 0);
            acc[1][1] = __builtin_amdgcn_mfma_f32_16x16x32_bf16(a1, b1, acc[1][1], 0, 0, 0);
        }
        __syncthreads();
    }
#pragma unroll
    for (int i = 0; i < 2; ++i)
#pragma unroll
        for (int q = 0; q < 4; ++q) {
            int row = m0 + wr * 32 + i * 16 + (lane >> 4) * 4 + q;
#pragma unroll
            for (int j = 0; j < 2; ++j) {
                int col = n0 + wc * 32 + j * 16 + (lane & 15);
                Cp[(size_t)row * LDP + col] = f2b(acc[i][j][q]);
            }
        }
}

// ---------------------------------------------------------------------------
// Batched step-7: out cols c_off.. = ctx_i @ Wo_i^T  (f32 out)
// grid = NB*240 (tiles per branch: 16,32,64,128), block 256.
// ---------------------------------------------------------------------------
__global__ __launch_bounds__(256)
void ogemm(const ushort* __restrict__ ctx,
           const ushort* __restrict__ O0, const ushort* __restrict__ O1,
           const ushort* __restrict__ O2, const ushort* __restrict__ O3,
           float* __restrict__ out)
{
    __shared__ ushort As[64 * 72];
    __shared__ ushort Bs[64 * 72];
    const int wg = xcd_swz(blockIdx.x, gridDim.x);
    const int b = wg / 240, tl = wg % 240;
    const int br = tl < 16 ? 0 : tl < 48 ? 1 : tl < 112 ? 2 : 3;
    const int st = br == 0 ? 0 : br == 1 ? 16 : br == 2 ? 48 : 112;
    const int loc = tl - st;
    const int csz[4]  = {64, 128, 256, 512};
    const int coff[4] = {0, 64, 192, 448};
    const ushort* op[4] = {O0, O1, O2, O3};
    const int c = csz[br];
    const int gxi = c / 64;
    const int xg = loc % gxi, yg = loc / gxi;   // yg 0..15
    const ushort* A = ctx + (size_t)b * PGE + coff[br];   // lda=LDP
    const ushort* B = op[br];                             // ldb=c
    float* Cf = out + (size_t)b * ((size_t)N_ * KV_) + coff[br];  // ldc=KV_
    const int m0 = yg * 64, n0 = xg * 64;
    const int t = threadIdx.x, lane = t & 63, wave = t >> 6;
    const int wr = wave >> 1, wc = wave & 1;

    f32x4 z4 = {0.f, 0.f, 0.f, 0.f};
    f32x4 acc[2][2]; acc[0][0] = z4; acc[0][1] = z4; acc[1][0] = z4; acc[1][1] = z4;

    for (int k0 = 0; k0 < c; k0 += 64) {
        stage64b(A, LDP, m0, k0, As, t);
        stage64b(B, c, n0, k0, Bs, t);
        __syncthreads();
        const int ar = wr * 32 + (lane & 15);
        const int brw = wc * 32 + (lane & 15);
        const int kg = (lane >> 4) * 8;
#pragma unroll
        for (int ks = 0; ks < 2; ++ks) {
            short8 a0 = *(const short8*)&As[(ar)      * 72 + ks * 32 + kg];
            short8 a1 = *(const short8*)&As[(ar + 16) * 72 + ks * 32 + kg];
            short8 b0 = *(const short8*)&Bs[(brw)      * 72 + ks * 32 + kg];
            short8 b1 = *(const short8*)&Bs[(brw + 16) * 72 + ks * 32 + kg];
            acc[0][0] = __builtin_amdgcn_mfma_f32_16x16x32_bf16(a0, b0, acc[0][0], 0, 0, 0);
            acc[0][1] = __builtin_amdgcn_mfma_f32_16x16x32_bf16(a0, b1, acc[0][1], 0, 0, 0);
            acc[1][0] = __builtin_amdgcn_mfma_f32_16x16x32_bf16(a1, b0, acc[1][0], 0, 0, 0);
            acc[1][1] = __builtin_amdgcn_mfma_f32_16x16x32_bf16(a1, b1, acc[1][1], 0, 0, 0);
        }
        __syncthreads();
    }
#pragma unroll
    for (int i = 0; i < 2; ++i)
#pragma unroll
        for (int q = 0; q < 4; ++q) {
            int row = m0 + wr * 32 + i * 16 + (lane >> 4) * 4 + q;
#pragma unroll
            for (int j = 0; j < 2; ++j) {
                int col = n0 + wc * 32 + j * 16 + (lane & 15);
                Cf[(size_t)row * KV_ + col] = acc[i][j][q];
            }
        }
}

// ---------------------------------------------------------------------------
// Batched weight convert: 8 segments (Wq x4, Wo x4), one launch.
// ---------------------------------------------------------------------------
struct WSeg { const float* s; ushort* d; unsigned n; };
struct WcvtA { WSeg seg[8]; };
__global__ __launch_bounds__(256)
void wcvt(WcvtA a)
{
    WSeg sg = a.seg[blockIdx.y];
    for (size_t i = ((size_t)blockIdx.x * 256 + threadIdx.x) * 4; i < sg.n;
         i += (size_t)gridDim.x * 1024) {
        float4v f = *(const float4v*)(sg.s + i);
        ushort4v v;
        v[0] = f2b(f[0]); v[1] = f2b(f[1]); v[2] = f2b(f[2]); v[3] = f2b(f[3]);
        *(ushort4v*)(sg.d + i) = v;
    }
}

// f32 (ld=sld) -> bf16 (ld=dld) re-strided convert; cols=960 (120 x ushort8)
__global__ __launch_bounds__(256)
void cvt_ld(const float* __restrict__ src, int sld, size_t sYsrc,
            ushort* __restrict__ dst, int dld, size_t sYdst, int total_chunks)
{
    const float* s0 = src + (size_t)blockIdx.y * sYsrc;
    ushort* d0 = dst + (size_t)blockIdx.y * sYdst;
    for (int ch = blockIdx.x * 256 + threadIdx.x; ch < total_chunks;
         ch += gridDim.x * 256) {
        int row = ch / 120, c = (ch % 120) * 8;
        const float* s = s0 + (size_t)row * sld + c;
        float4v f0 = *(const float4v*)s;
        float4v f1 = *(const float4v*)(s + 4);
        ushort8 v;
        v[0] = f2b(f0[0]); v[1] = f2b(f0[1]); v[2] = f2b(f0[2]); v[3] = f2b(f0[3]);
        v[4] = f2b(f1[0]); v[5] = f2b(f1[1]); v[6] = f2b(f1[2]); v[7] = f2b(f1[3]);
        *(ushort8*)(d0 + (size_t)row * dld + c) = v;
    }
}

// ---------------------------------------------------------------------------
// Generic f32 [R][C] -> bf16 [C][R] tile transpose+convert (used for WvT).
// ---------------------------------------------------------------------------
__global__ __launch_bounds__(256)
void tposecvt(const float* __restrict__ src, size_t sSrc, int sld,
              ushort* __restrict__ dst, size_t sDst, int dld)
{
    __shared__ ushort tile[32][33];
    const float* s = src + (size_t)blockIdx.z * sSrc;
    ushort* d = dst + (size_t)blockIdx.z * sDst;
    int c0 = blockIdx.x * 32, r0 = blockIdx.y * 32;
    for (int i = threadIdx.y; i < 32; i += 8)
        tile[i][threadIdx.x] = f2b(s[(size_t)(r0 + i) * sld + c0 + threadIdx.x]);
    __syncthreads();
    for (int i = threadIdx.y; i < 32; i += 8)
        d[(size_t)(c0 + i) * dld + r0 + threadIdx.x] = tile[threadIdx.x][i];
}

// ---------------------------------------------------------------------------
// Fused per-group conversion: one launch covers
//   x-tile <15 : emb_all -> EA [n][m] + EAT [m][n]  (dualcvt tiles)
//   x-tile >=15: emb_cat -> embT [p][n]             (embtall tiles)
// grid (30, 16, NB), block (64,4), f32 LDS [64][65].
// ---------------------------------------------------------------------------
__global__ __launch_bounds__(256)
void cvtall(const float* __restrict__ ea_src, ushort* __restrict__ ea, size_t sEA,
            ushort* __restrict__ eat, size_t sEAT,
            const float* __restrict__ e0, const float* __restrict__ e1,
            const float* __restrict__ e2, const float* __restrict__ e3,
            ushort* __restrict__ embT)
{
    __shared__ float tile[64][65];
    int tx = threadIdx.x, ty = threadIdx.y;
    if (blockIdx.x < 15) {
        // dualcvt tile
        const float* s = ea_src + (size_t)blockIdx.z * ((size_t)N_ * KV_);
        ushort* pea  = ea  + (size_t)blockIdx.z * sEA;
        ushort* peat = eat + (size_t)blockIdx.z * sEAT;
        int m0 = blockIdx.x * 64, n0 = blockIdx.y * 64;
        for (int i = ty; i < 64; i += 4) {
            float v = s[(size_t)(n0 + i) * KV_ + m0 + tx];
            tile[i][tx] = v;
            pea[(size_t)(n0 + i) * LDP + m0 + tx] = f2b(v);
        }
        __syncthreads();
        for (int i = ty; i < 64; i += 4)
            peat[(size_t)(m0 + i) * LDP + n0 + tx] = f2b(tile[tx][i]);
    } else {
        // embtall tile
        const int xt = blockIdx.x - 15;
        const int br = xt < 1 ? 0 : xt < 3 ? 1 : xt < 7 ? 2 : 3;
        const int st = br == 0 ? 0 : br == 1 ? 1 : br == 2 ? 3 : 7;
        const int loc = xt - st;
        const int csz[4]  = {64, 128, 256, 512};
        const int coff[4] = {0, 64, 192, 448};
        const float* ep[4] = {e0, e1, e2, e3};
        const int c = csz[br];
        const float* s = ep[br] + (size_t)blockIdx.z * ((size_t)N_ * c);
        ushort* d = embT + (size_t)blockIdx.z * (2 * PGE) + (size_t)coff[br] * LDP;
        int c0 = loc * 64, r0 = blockIdx.y * 64;
        for (int i = ty; i < 64; i += 4)
            tile[i][tx] = s[(size_t)(r0 + i) * c + c0 + tx];
        __syncthreads();
        for (int i = ty; i < 64; i += 4)
            d[(size_t)(c0 + i) * LDP + r0 + tx] = f2b(tile[tx][i]);
    }
}

// ---------------------------------------------------------------------------
// Final stats from per-tile partials (fixed order => deterministic).
// grid NB*H*4 (z = bh*4+br), block 64. 32 tiles per (b,h) slab.
// ---------------------------------------------------------------------------
__global__ __launch_bounds__(64)
void normstats2b(const float2v* __restrict__ parts, float* __restrict__ stats)
{
    const int z = blockIdx.x;
    const int bh = z >> 2, br = z & 3;
    const int csz[4] = {64, 128, 256, 512};
    if (threadIdx.x == 0) {
        float s = 0.f, s2 = 0.f;
        const float2v* p = parts + (size_t)bh * 128 + br;
        for (int t = 0; t < 32; ++t) {
            float2v r = p[t * 4];
            s += r[0]; s2 += r[1];
        }
        const float inv_cnt = 1.0f / (float)(csz[br] * KV_);
        float mu  = s * inv_cnt;
        float var = s2 * inv_cnt - mu * mu;
        stats[2 * z]     = mu;
        stats[2 * z + 1] = rsqrtf(var + 1e-5f);
    }
}

// ---------------------------------------------------------------------------
// Row softmax, in place on bf16 scores. NO max-subtraction: inputs are
// InstanceNorm-normalized (unit variance) so |x| <~ 10 and exp() cannot
// overflow f32 (limit 88); result is mathematically identical.
// ---------------------------------------------------------------------------
__global__ __launch_bounds__(256)
void psoftmax(ushort* __restrict__ S, const float* __restrict__ stats)
{
    const int r  = blockIdx.x;
    const int bh  = r / KV_;
    const int row = r % KV_;
    const int br  = (row < 64) ? 0 : (row < 192) ? 1 : (row < 448) ? 2 : 3;
    const float mu = stats[2 * (bh * 4 + br)];
    const float rs = stats[2 * (bh * 4 + br) + 1];
    ushort* p = S + (size_t)bh * PGE + (size_t)row * LDP;

    const int t = threadIdx.x;
    float x[4];
    float s = 0.f;
#pragma unroll
    for (int i = 0; i < 4; ++i) {
        int idx = t + i * 256;
        x[i] = (idx < KV_) ? __expf((b2f(p[idx]) - mu) * rs) : 0.f;
        s += x[i];
    }
#pragma unroll
    for (int o = 1; o < 64; o <<= 1) s += __shfl_xor(s, o);
    __shared__ float wsum[4];
    int w = t >> 6, l = t & 63;
    if (l == 0) wsum[w] = s;
    __syncthreads();
    s = wsum[0] + wsum[1] + wsum[2] + wsum[3];
    float inv = 1.0f / s;
#pragma unroll
    for (int i = 0; i < 4; ++i) {
        int idx = t + i * 256;
        if (idx < KV_) p[idx] = f2b(x[i] * inv);
    }
}

// ---------------------------------------------------------------------------
extern "C" void kernel_launch(void* const* d_in, const int* in_sizes, int n_in,
                              void* d_out, int out_size, void* d_ws, size_t ws_size,
                              hipStream_t stream)
{
    const float* emb[4] = {(const float*)d_in[0], (const float*)d_in[1],
                           (const float*)d_in[2], (const float*)d_in[3]};
    const float* emb_all = (const float*)d_in[4];
    const float* Wq[4] = {(const float*)d_in[5], (const float*)d_in[7],
                          (const float*)d_in[9], (const float*)d_in[11]};
    const float* Wo[4] = {(const float*)d_in[6], (const float*)d_in[8],
                          (const float*)d_in[10], (const float*)d_in[12]};
    const float* Wk = (const float*)d_in[13];
    const float* Wv = (const float*)d_in[14];
    float* out = (float*)d_out;

    const int c_sz[4]  = {64, 128, 256, 512};

    const size_t BN  = (size_t)N_ * KV_;     // 983040
    const size_t GE9 = (size_t)KV_ * KV_;    // 921600
    const float SCALE = 0.03227486121839514f;  // 1/sqrt(960)

    char* wsp = (char*)d_ws;
    size_t off = 0;
    auto alloc = [&](size_t bytes) -> char* {
        off = (off + 255) & ~(size_t)255;
        char* p = wsp + off;
        off += bytes;
        return p;
    };

    // Static: bf16 weights
    ushort* WqB[4]; ushort* WoB[4];
    for (int i = 0; i < 4; ++i) WqB[i] = (ushort*)alloc((size_t)2 * c_sz[i] * c_sz[i] * 2);
    for (int i = 0; i < 4; ++i) WoB[i] = (ushort*)alloc((size_t)c_sz[i] * c_sz[i] * 2);
    ushort* WkB = (ushort*)alloc(2 * PGE * 2);   // [2][1024][LDP]
    ushort* WvT = (ushort*)alloc(2 * PGE * 2);   // [2][m][k] bf16, LD=LDP

    {
        WcvtA a;
        for (int i = 0; i < 4; ++i) {
            a.seg[i]     = { Wq[i], WqB[i], (unsigned)(2 * c_sz[i] * c_sz[i]) };
            a.seg[4 + i] = { Wo[i], WoB[i], (unsigned)(c_sz[i] * c_sz[i]) };
        }
        wcvt<<<dim3(64, 8), 256, 0, stream>>>(a);
    }
    cvt_ld<<<dim3(450, 2), 256, 0, stream>>>(Wk, KV_, GE9, WkB, LDP, PGE, 960 * 120);
    tposecvt<<<dim3(30, 30, 2), dim3(32, 8), 0, stream>>>(Wv, GE9, KV_, WvT, PGE, LDP);

    // Per-batch slots with aliasing: slotA PGE (G2/ctx) ; Y 2*PGE (embT->Y->R) ;
    // Sc 2*PGE (EAT -> scores/P) ; EA PGE  => 6*PGE*2B = 12 MB/batch
    const size_t perB = 6 * PGE * 2;
    size_t statik = (off + 255) & ~(size_t)255;
    int NB = 16;
    while (NB > 1 && statik + (size_t)NB * perB + 262144 > ws_size) NB >>= 1;

    ushort* slotA = (ushort*)alloc((size_t)NB * PGE * 2);       // G2 / ctx
    ushort* Y     = (ushort*)alloc((size_t)NB * 2 * PGE * 2);   // embT -> Y -> R
    ushort* Sc    = (ushort*)alloc((size_t)NB * 2 * PGE * 2);   // EAT -> scores/P
    ushort* EA    = (ushort*)alloc((size_t)NB * PGE * 2);       // emb_all bf16 [n][m]
    float*  stats = (float*) alloc((size_t)NB * 2 * 4 * 2 * 4);
    float2v* parts = (float2v*)alloc((size_t)NB * 2 * 64 * 4 * 8);
    ushort* EAT  = Sc;   // [NB][1024][LDP], batch stride 2*PGE — dead after step 1
    ushort* embT = Y;    // [NB][1024][LDP], batch stride 2*PGE — dead after step 1
    ushort* R    = Y;    // [NB][1024][LDP], batch stride 2*PGE after step 5

    for (int b0 = 0; b0 < B_; b0 += NB) {
        // 0) EA + EAT + embT in ONE launch (fused conversion/transpose)
        cvtall<<<dim3(30, 16, NB), dim3(64, 4), 0, stream>>>(
            emb_all + (size_t)b0 * BN, EA, PGE, EAT, 2 * PGE,
            emb[0] + (size_t)b0 * N_ * 64,  emb[1] + (size_t)b0 * N_ * 128,
            emb[2] + (size_t)b0 * N_ * 256, emb[3] + (size_t)b0 * N_ * 512,
            embT);

        // 1) G2[m,p] = sum_n EA[n,m]*emb_cat[n,p]  (256x128-path, K=1024)
        gemm256<1, false, false><<<dim3(8 * 4 * NB), 512, 0, stream>>>(
            8, 4, N_, 1.0f,
            EAT, 2 * PGE, 0,
            embT, 2 * PGE, 0,
            slotA, LDP, PGE, 0, /*hsel=*/0, nullptr);

        // 2) Y = Wq @ G2 (all branches, one launch)
        ygemm<<<dim3(NB * 2 * 225), 256, 0, stream>>>(
            WqB[0], WqB[1], WqB[2], WqB[3], slotA, Y);

        // 3) scores bf16 = SCALE * Y @ Wk[h]^T  + fused stats partials
        gemm256<1, false, true><<<dim3(8 * 4 * NB * H_), 512, 0, stream>>>(
            8, 4, KV_, SCALE,
            Y, 2 * PGE, PGE,
            WkB, 0, PGE,
            Sc, LDP, 2 * PGE, PGE, /*hsel=*/-1, parts);

        // 4) finalize stats + in-place softmax on Sc
        normstats2b<<<NB * H_ * 4, 64, 0, stream>>>(parts, stats);
        psoftmax<<<NB * H_ * KV_, 256, 0, stream>>>(Sc, stats);

        // 5) R[p,m] = sum_h P[b,h] @ WvT[h] rows  (256x128-path, HSUM=2)
        gemm256<2, false, false><<<dim3(8 * 4 * NB), 512, 0, stream>>>(
            8, 4, KV_, 1.0f,
            Sc, 2 * PGE, PGE,
            WvT, 0, PGE,
            R, LDP, 2 * PGE, 0, /*hsel=*/0, nullptr);

        // 6) ctx[n,p] = 0.5 * EA @ R^T  (256x128-path)
        gemm256<1, false, false><<<dim3(8 * 4 * NB), 512, 0, stream>>>(
            8, 4, KV_, 0.5f,
            EA, PGE, 0,
            R, 2 * PGE, 0,
            slotA, LDP, PGE, 0, /*hsel=*/0, nullptr);

        // 7) out = ctx @ Wo^T (all branches, one launch, f32)
        ogemm<<<dim3(NB * 240), 256, 0, stream>>>(
            slotA, WoB[0], WoB[1], WoB[2], WoB[3],
            out + (size_t)b0 * BN);
    }
}